// Round 13
// baseline (76.138 us; speedup 1.0000x reference)
//
#include <hip/hip_runtime.h>
#include <math.h>

// Problem constants: B=8, C=128, H=W=128, HEADS=8
#define N_     16384          // H*W
#define N4     4096           // N_/4 (float4 units per row)
#define BHN    64             // B*HEADS
#define CH     16             // channels per head (hk == hv)
#define ROWS   1024           // B*C
#define CHUNKS 64             // col chunks for k_ctx (256 cols each)

typedef __attribute__((ext_vector_type(8))) short short8;   // 8 x bf16
typedef __attribute__((ext_vector_type(4))) float f32x4;

static __device__ __forceinline__ short f2bf(float f) {
    __bf16 b = (__bf16)f;                      // v_cvt f32->bf16 (RNE)
    return __builtin_bit_cast(short, b);
}

// ---- primary-path ws layout (bytes):
//   e_bf : 1024*16384 shorts = 32 MB   (exp'd keys, bf16)
//   v_bf : 1024*16384 shorts = 32 MB   (values, bf16)
//   z    : 1024 floats                 (exact fp32 row sums of exp)
//   part : 64*64*256 floats = 4 MB     (per-chunk context partials)
#define WS_NEED ((size_t)ROWS * N_ * 2 * 2 + ROWS * 4 + (size_t)BHN * CHUNKS * 256 * 4)

// ================================================================ PRIMARY
// ---------------------------------------------------------------- k_prep
// PURE STREAM (the ablation): block = one row r of both arrays. Load 32B
// contiguous per thread (2 adjacent float4), exp for x2 (fp32 Z per row
// BEFORE bf16 rounding -> Z exact), cvt, store short8. No LDS in the hot
// path, no MFMA, no tile consumption -- isolates the HBM read from all
// structure. If this also runs at ~1.5 TB/s the slow-read is environmental.
__global__ __launch_bounds__(256) void k_prep(const float* __restrict__ x1,
                                              const float* __restrict__ x2,
                                              short* __restrict__ e_bf,
                                              short* __restrict__ v_bf,
                                              float* __restrict__ z) {
    int row = blockIdx.x;
    int tid = threadIdx.x;
    int w = tid >> 6, l = tid & 63;

    __shared__ float zred[4];

    // ---- x2 row -> exp -> e_bf
    {
        const float4* p = (const float4*)(x2 + (size_t)row * N_);
        short8* q = (short8*)(e_bf + (size_t)row * N_);
        float zacc = 0.f;
        #pragma unroll
        for (int it = 0; it < 4; ++it) {
            int i0 = it * 1024 + 2 * tid;        // pass 2*it
            int i1 = i0 + 512;                   // pass 2*it+1
            float4 a0 = p[i0], a1 = p[i0 + 1];   // 4 independent loads
            float4 b0 = p[i1], b1 = p[i1 + 1];
            float e0=__expf(a0.x), e1=__expf(a0.y), e2=__expf(a0.z), e3=__expf(a0.w);
            float e4=__expf(a1.x), e5=__expf(a1.y), e6=__expf(a1.z), e7=__expf(a1.w);
            float f0=__expf(b0.x), f1=__expf(b0.y), f2=__expf(b0.z), f3=__expf(b0.w);
            float f4=__expf(b1.x), f5=__expf(b1.y), f6=__expf(b1.z), f7=__expf(b1.w);
            zacc += (((e0+e1)+(e2+e3)) + ((e4+e5)+(e6+e7)))
                  + (((f0+f1)+(f2+f3)) + ((f4+f5)+(f6+f7)));
            short8 s0 = {f2bf(e0),f2bf(e1),f2bf(e2),f2bf(e3),
                         f2bf(e4),f2bf(e5),f2bf(e6),f2bf(e7)};
            short8 s1 = {f2bf(f0),f2bf(f1),f2bf(f2),f2bf(f3),
                         f2bf(f4),f2bf(f5),f2bf(f6),f2bf(f7)};
            q[i0 >> 1] = s0;
            q[i1 >> 1] = s1;
        }
        #pragma unroll
        for (int off = 1; off < 64; off <<= 1) zacc += __shfl_xor(zacc, off);
        if (l == 0) zred[w] = zacc;
    }
    // ---- x1 row -> v_bf (no exp, no Z)
    {
        const float4* p = (const float4*)(x1 + (size_t)row * N_);
        short8* q = (short8*)(v_bf + (size_t)row * N_);
        #pragma unroll
        for (int it = 0; it < 4; ++it) {
            int i0 = it * 1024 + 2 * tid;
            int i1 = i0 + 512;
            float4 a0 = p[i0], a1 = p[i0 + 1];
            float4 b0 = p[i1], b1 = p[i1 + 1];
            short8 s0 = {f2bf(a0.x),f2bf(a0.y),f2bf(a0.z),f2bf(a0.w),
                         f2bf(a1.x),f2bf(a1.y),f2bf(a1.z),f2bf(a1.w)};
            short8 s1 = {f2bf(b0.x),f2bf(b0.y),f2bf(b0.z),f2bf(b0.w),
                         f2bf(b1.x),f2bf(b1.y),f2bf(b1.z),f2bf(b1.w)};
            q[i0 >> 1] = s0;
            q[i1 >> 1] = s1;
        }
    }
    __syncthreads();
    if (tid == 0) z[row] = (zred[0] + zred[1]) + (zred[2] + zred[3]);
}

// ---------------------------------------------------------------- k_ctx
// One-shot MFMA over bf16 data that k_prep JUST wrote (L3-hot -> the fast
// regime k_attend demonstrates). Block (chunk,bh): 16x256 bf16 tile pair,
// 2 staging passes/array, one barrier, 2 K=32 MFMA steps per wave on
// disjoint 64-col slices, cross-wave sum, store partial.
__global__ __launch_bounds__(256) void k_ctx(const short* __restrict__ e_bf,
                                             const short* __restrict__ v_bf,
                                             float* __restrict__ part) {
    int chunk = blockIdx.x;   // 0..63
    int bh    = blockIdx.y;   // 0..63
    int tid   = threadIdx.x;
    int w = tid >> 6, l = tid & 63;

    __shared__ __align__(16) short es[16 * 264];   // pad 264: frag reads 2-way
    __shared__ __align__(16) short vs[16 * 264];
    __shared__ float cred[4][256];

    #pragma unroll
    for (int p = 0; p < 2; ++p) {
        int idx = p * 256 + tid;
        int row = idx >> 5, grp = idx & 31;
        size_t g = (size_t)(bh * CH + row) * N_ + chunk * 256 + grp * 8;
        *(short8*)&es[row * 264 + grp * 8] = *(const short8*)(e_bf + g);
        *(short8*)&vs[row * 264 + grp * 8] = *(const short8*)(v_bf + g);
    }
    __syncthreads();

    int row16 = l & 15;               // kk for A, vv for B
    int q     = l >> 4;
    f32x4 acc = {0.f, 0.f, 0.f, 0.f};
    #pragma unroll
    for (int s = 0; s < 2; ++s) {
        int col = w * 64 + s * 32 + q * 8;
        short8 af = *(const short8*)&es[row16 * 264 + col];
        short8 bv = *(const short8*)&vs[row16 * 264 + col];
        acc = __builtin_amdgcn_mfma_f32_16x16x32_bf16(af, bv, acc, 0, 0, 0);
    }

    // D layout (m89-verified): lane l, reg r -> ctx[(l>>4)*4 + r][l&15]
    #pragma unroll
    for (int r = 0; r < 4; ++r)
        cred[w][(q * 4 + r) * 16 + row16] = acc[r];
    __syncthreads();

    float c = (cred[0][tid] + cred[1][tid]) + (cred[2][tid] + cred[3][tid]);
    part[(size_t)(bh * CHUNKS + chunk) * 256 + tid] = c;   // [kk*16+vv]
}

// ---------------------------------------------------------------- k_attend
__global__ __launch_bounds__(256) void k_attend(const float* __restrict__ x2,
                                                const float* __restrict__ part,
                                                const float* __restrict__ z,
                                                float* __restrict__ out) {
    int cb  = blockIdx.x;   // 0..63
    int bh  = blockIdx.y;   // 0..63
    int tid = threadIdx.x;

    __shared__ float q_s[16][256];
    __shared__ float ctxs[256];
    __shared__ float rzs[16];

    float csum = 0.f;
    #pragma unroll
    for (int c = 0; c < CHUNKS; ++c)
        csum += part[(size_t)(bh * CHUNKS + c) * 256 + tid];
    if (tid < 16) rzs[tid] = 1.0f / z[bh * CH + tid];

    const float4* px = (const float4*)(x2 + (size_t)bh * CH * N_);
    int base4 = cb * 64;
    #pragma unroll
    for (int r = 0; r < 4; ++r) {
        int idx = r * 256 + tid;
        int ch = idx >> 6, j = idx & 63;
        float4 v = px[(size_t)ch * N4 + base4 + j];
        *(float4*)&q_s[ch][j * 4] = v;
    }
    __syncthreads();

    ctxs[tid] = csum * rzs[tid >> 4];

    {   // channel softmax per column
        int col = tid;
        float kv[16];
        #pragma unroll
        for (int c = 0; c < 16; ++c) kv[c] = q_s[c][col];
        float mx = kv[0];
        #pragma unroll
        for (int c = 1; c < 16; ++c) mx = fmaxf(mx, kv[c]);
        float s = 0.f;
        #pragma unroll
        for (int c = 0; c < 16; ++c) { kv[c] = __expf(kv[c] - mx); s += kv[c]; }
        float rs = 1.0f / s;
        #pragma unroll
        for (int c = 0; c < 16; ++c) q_s[c][col] = kv[c] * rs;
    }
    __syncthreads();

    int vg = tid >> 6, cq = tid & 63;
    int vv0 = vg * 4, c0 = cq * 4;
    float4 a0 = make_float4(0.f,0.f,0.f,0.f);
    float4 a1 = a0, a2 = a0, a3 = a0;
    #pragma unroll
    for (int kk = 0; kk < 16; ++kk) {
        float4 cx = *(const float4*)&ctxs[kk * 16 + vv0];
        float4 q4 = *(const float4*)&q_s[kk][c0];
        a0.x = fmaf(q4.x, cx.x, a0.x); a0.y = fmaf(q4.x, cx.y, a0.y);
        a0.z = fmaf(q4.x, cx.z, a0.z); a0.w = fmaf(q4.x, cx.w, a0.w);
        a1.x = fmaf(q4.y, cx.x, a1.x); a1.y = fmaf(q4.y, cx.y, a1.y);
        a1.z = fmaf(q4.y, cx.z, a1.z); a1.w = fmaf(q4.y, cx.w, a1.w);
        a2.x = fmaf(q4.z, cx.x, a2.x); a2.y = fmaf(q4.z, cx.y, a2.y);
        a2.z = fmaf(q4.z, cx.z, a2.z); a2.w = fmaf(q4.z, cx.w, a2.w);
        a3.x = fmaf(q4.w, cx.x, a3.x); a3.y = fmaf(q4.w, cx.y, a3.y);
        a3.z = fmaf(q4.w, cx.z, a3.z); a3.w = fmaf(q4.w, cx.w, a3.w);
    }
    size_t outbase = (size_t)bh * CH * N_ + (size_t)cb * 256 + c0;
    float4 o;
    o = make_float4(a0.x, a1.x, a2.x, a3.x);
    *(float4*)&out[outbase + (size_t)(vv0 + 0) * N_] = o;
    o = make_float4(a0.y, a1.y, a2.y, a3.y);
    *(float4*)&out[outbase + (size_t)(vv0 + 1) * N_] = o;
    o = make_float4(a0.z, a1.z, a2.z, a3.z);
    *(float4*)&out[outbase + (size_t)(vv0 + 2) * N_] = o;
    o = make_float4(a0.w, a1.w, a2.w, a3.w);
    *(float4*)&out[outbase + (size_t)(vv0 + 3) * N_] = o;
}

// ================================================================ FALLBACK
// Round-12 known-good path (used only if ws_size < WS_NEED).
#define FCHUNKS 32
#define FWS_PART 0
#define FWS_ZP   (BHN * FCHUNKS * 256)

__global__ __launch_bounds__(256) void k_ctx_fb(const float* __restrict__ x1,
                                                const float* __restrict__ x2,
                                                float* __restrict__ ws) {
    int chunk = blockIdx.x, bh = blockIdx.y;
    int tid = threadIdx.x;
    int w = tid >> 6, l = tid & 63;
    __shared__ __align__(16) short e_s[16][520];
    __shared__ __align__(16) short v_s[16][520];
    __shared__ float cred[4][256];
    __shared__ float zs[16];
    {
        const float* src = (w < 2) ? x2 : x1;
        int r0 = (w & 1) * 8;
        const float* base = src + (size_t)(bh * CH + r0) * N_ + chunk * 512;
        float4 A[16];
        #pragma unroll
        for (int i = 0; i < 8; ++i) {
            const float4* p = (const float4*)(base + (size_t)i * N_);
            A[2 * i] = p[2 * l]; A[2 * i + 1] = p[2 * l + 1];
        }
        if (w < 2) {
            #pragma unroll
            for (int i = 0; i < 8; ++i) {
                float4 a = A[2 * i], b = A[2 * i + 1];
                float e0=__expf(a.x), e1=__expf(a.y), e2=__expf(a.z), e3=__expf(a.w);
                float e4=__expf(b.x), e5=__expf(b.y), e6=__expf(b.z), e7=__expf(b.w);
                float zz = ((e0+e1)+(e2+e3)) + ((e4+e5)+(e6+e7));
                #pragma unroll
                for (int off = 1; off < 64; off <<= 1) zz += __shfl_xor(zz, off);
                if (l == 0) zs[r0 + i] = zz;
                short8 pk = {f2bf(e0),f2bf(e1),f2bf(e2),f2bf(e3),
                             f2bf(e4),f2bf(e5),f2bf(e6),f2bf(e7)};
                *(short8*)&e_s[r0 + i][l * 8] = pk;
            }
        } else {
            #pragma unroll
            for (int i = 0; i < 8; ++i) {
                float4 a = A[2 * i], b = A[2 * i + 1];
                short8 pv = {f2bf(a.x),f2bf(a.y),f2bf(a.z),f2bf(a.w),
                             f2bf(b.x),f2bf(b.y),f2bf(b.z),f2bf(b.w)};
                *(short8*)&v_s[r0 + i][l * 8] = pv;
            }
        }
    }
    __syncthreads();
    int row16 = l & 15, q = l >> 4;
    f32x4 acc = {0.f, 0.f, 0.f, 0.f};
    #pragma unroll
    for (int s = 0; s < 4; ++s) {
        int col = w * 128 + s * 32 + q * 8;
        short8 af = *(const short8*)&e_s[row16][col];
        short8 bv = *(const short8*)&v_s[row16][col];
        acc = __builtin_amdgcn_mfma_f32_16x16x32_bf16(af, bv, acc, 0, 0, 0);
    }
    #pragma unroll
    for (int r = 0; r < 4; ++r)
        cred[w][(q * 4 + r) * 16 + row16] = acc[r];
    __syncthreads();
    if (tid < 16) ws[FWS_ZP + (bh * FCHUNKS + chunk) * 16 + tid] = zs[tid];
    float c = (cred[0][tid] + cred[1][tid]) + (cred[2][tid] + cred[3][tid]);
    ws[FWS_PART + (size_t)(bh * FCHUNKS + chunk) * 256 + tid] = c;
}

__global__ __launch_bounds__(256) void k_attend_fb(const float* __restrict__ x2,
                                                   const float* __restrict__ ws,
                                                   float* __restrict__ out) {
    int cb = blockIdx.x, bh = blockIdx.y;
    int tid = threadIdx.x;
    __shared__ float q_s[16][256];
    __shared__ float ctxs[256];
    __shared__ float rzs[16];
    float csum = 0.f;
    #pragma unroll
    for (int c = 0; c < FCHUNKS; ++c)
        csum += ws[FWS_PART + (size_t)(bh * FCHUNKS + c) * 256 + tid];
    if (tid < 16) {
        float z = 0.f;
        #pragma unroll
        for (int c = 0; c < FCHUNKS; ++c)
            z += ws[FWS_ZP + (bh * FCHUNKS + c) * 16 + tid];
        rzs[tid] = 1.0f / z;
    }
    const float4* px = (const float4*)(x2 + (size_t)bh * CH * N_);
    int base4 = cb * 64;
    #pragma unroll
    for (int r = 0; r < 4; ++r) {
        int idx = r * 256 + tid;
        int ch = idx >> 6, j = idx & 63;
        float4 v = px[(size_t)ch * N4 + base4 + j];
        *(float4*)&q_s[ch][j * 4] = v;
    }
    __syncthreads();
    ctxs[tid] = csum * rzs[tid >> 4];
    {
        int col = tid;
        float kv[16];
        #pragma unroll
        for (int c = 0; c < 16; ++c) kv[c] = q_s[c][col];
        float mx = kv[0];
        #pragma unroll
        for (int c = 1; c < 16; ++c) mx = fmaxf(mx, kv[c]);
        float s = 0.f;
        #pragma unroll
        for (int c = 0; c < 16; ++c) { kv[c] = __expf(kv[c] - mx); s += kv[c]; }
        float rs = 1.0f / s;
        #pragma unroll
        for (int c = 0; c < 16; ++c) q_s[c][col] = kv[c] * rs;
    }
    __syncthreads();
    int vg = tid >> 6, cq = tid & 63;
    int vv0 = vg * 4, c0 = cq * 4;
    float4 a0 = make_float4(0.f,0.f,0.f,0.f);
    float4 a1 = a0, a2 = a0, a3 = a0;
    #pragma unroll
    for (int kk = 0; kk < 16; ++kk) {
        float4 cx = *(const float4*)&ctxs[kk * 16 + vv0];
        float4 q4 = *(const float4*)&q_s[kk][c0];
        a0.x = fmaf(q4.x, cx.x, a0.x); a0.y = fmaf(q4.x, cx.y, a0.y);
        a0.z = fmaf(q4.x, cx.z, a0.z); a0.w = fmaf(q4.x, cx.w, a0.w);
        a1.x = fmaf(q4.y, cx.x, a1.x); a1.y = fmaf(q4.y, cx.y, a1.y);
        a1.z = fmaf(q4.y, cx.z, a1.z); a1.w = fmaf(q4.y, cx.w, a1.w);
        a2.x = fmaf(q4.z, cx.x, a2.x); a2.y = fmaf(q4.z, cx.y, a2.y);
        a2.z = fmaf(q4.z, cx.z, a2.z); a2.w = fmaf(q4.z, cx.w, a2.w);
        a3.x = fmaf(q4.w, cx.x, a3.x); a3.y = fmaf(q4.w, cx.y, a3.y);
        a3.z = fmaf(q4.w, cx.z, a3.z); a3.w = fmaf(q4.w, cx.w, a3.w);
    }
    size_t outbase = (size_t)bh * CH * N_ + (size_t)cb * 256 + c0;
    float4 o;
    o = make_float4(a0.x, a1.x, a2.x, a3.x);
    *(float4*)&out[outbase + (size_t)(vv0 + 0) * N_] = o;
    o = make_float4(a0.y, a1.y, a2.y, a3.y);
    *(float4*)&out[outbase + (size_t)(vv0 + 1) * N_] = o;
    o = make_float4(a0.z, a1.z, a2.z, a3.z);
    *(float4*)&out[outbase + (size_t)(vv0 + 2) * N_] = o;
    o = make_float4(a0.w, a1.w, a2.w, a3.w);
    *(float4*)&out[outbase + (size_t)(vv0 + 3) * N_] = o;
}

// ---------------------------------------------------------------- launch
extern "C" void kernel_launch(void* const* d_in, const int* in_sizes, int n_in,
                              void* d_out, int out_size, void* d_ws, size_t ws_size,
                              hipStream_t stream) {
    const float* x1 = (const float*)d_in[0];   // values
    const float* x2 = (const float*)d_in[1];   // keys / queries
    float* out = (float*)d_out;

    if (ws_size >= WS_NEED) {
        short* e_bf = (short*)d_ws;
        short* v_bf = e_bf + (size_t)ROWS * N_;
        float* z    = (float*)(v_bf + (size_t)ROWS * N_);
        float* part = z + ROWS;
        k_prep  <<<ROWS,             256, 0, stream>>>(x1, x2, e_bf, v_bf, z);
        k_ctx   <<<dim3(CHUNKS, BHN), 256, 0, stream>>>(e_bf, v_bf, part);
        k_attend<<<dim3(64, BHN),    256, 0, stream>>>(x2, part, z, out);
    } else {
        float* ws = (float*)d_ws;
        k_ctx_fb   <<<dim3(FCHUNKS, BHN), 256, 0, stream>>>(x1, x2, ws);
        k_attend_fb<<<dim3(64, BHN),      256, 0, stream>>>(x2, ws, out);
    }
}

// Round 14
// 57.502 us; speedup vs baseline: 1.3241x; 1.3241x over previous
//
#include <hip/hip_runtime.h>
#include <math.h>

// Problem constants: B=8, C=128, H=W=128, HEADS=8
#define N_     16384          // H*W
#define N4     4096           // N_/4 (float4 units per row)
#define BHN    64             // B*HEADS
#define CH     16             // channels per head (hk == hv)
#define CHUNKS 32             // col chunks for k_ctx (512 cols each)

// ws layout (in floats):
//   part[64*32*256] : unnormalized partial context per (bh, chunk)   2 MB
//   zp  [64*32*16]  : unnormalized partial row-sums               128 KB
#define WS_PART 0
#define WS_ZP   (BHN * CHUNKS * 256)

typedef __attribute__((ext_vector_type(8))) short short8;   // 8 x bf16
typedef __attribute__((ext_vector_type(4))) float f32x4;

static __device__ __forceinline__ short f2bf(float f) {
    __bf16 b = (__bf16)f;                      // v_cvt f32->bf16 (RNE)
    return __builtin_bit_cast(short, b);
}

// ---------------------------------------------------------------- kernel B
// ctx_part[kk][vv] = sum_{n in strip} exp(k[kk,n]) * v[vv,n]  via bf16 MFMA.
// MLP FIX (the round-13 diagnosis): r13's pure-stream ablation showed even
// a structureless reader crawls at 2.3 TB/s with VGPR_Count=32 -- the
// register allocator serializes every load burst to ~3 in flight/wave;
// Little's law (3 KB in flight/CU vs 9.2 KB needed at ~375ns HBM latency)
// predicts exactly the measured 2.1-2.3 TB/s. This kernel is r12 verbatim
// with TWO changes only:
//   1. __launch_bounds__(256, 2): VGPR budget 256/wave so A[16] (64 VGPRs
//      of load payload) stays live -> 16 loads in flight per wave.
//   2. sched_barrier(0) between the load burst and consumption: the
//      compiler cannot sink loads into the use chain.
// Staging roles (r12): wave 0: x2 rows 0-7 (exp, fp32 Z, bf16); wave 1:
// x2 rows 8-15; wave 2: x1 rows 0-7; wave 3: x1 rows 8-15. One barrier;
// 4 MFMA K-steps per wave on disjoint 128-col slices; cross-wave sum.
__global__ __launch_bounds__(256, 2) void k_ctx_mfma(const float* __restrict__ x1,
                                                     const float* __restrict__ x2,
                                                     float* __restrict__ ws) {
    int chunk = blockIdx.x;   // 0..31 (512-col strip)
    int bh    = blockIdx.y;   // 0..63
    int tid   = threadIdx.x;
    int w = tid >> 6, l = tid & 63;

    __shared__ __align__(16) short e_s[16][520];   // exp'd keys, bf16
    __shared__ __align__(16) short v_s[16][520];   // values, bf16
    __shared__ float cred[4][256];
    __shared__ float zs[16];

    // ---- wave-specialized staging: ONE array per wave, 16 loads in flight
    {
        const float* src = (w < 2) ? x2 : x1;
        int r0 = (w & 1) * 8;                       // rows r0..r0+7
        const float* base = src + (size_t)(bh * CH + r0) * N_ + chunk * 512;

        float4 A[16];                                // 16 independent loads
        #pragma unroll
        for (int i = 0; i < 8; ++i) {
            const float4* p = (const float4*)(base + (size_t)i * N_);
            A[2 * i]     = p[2 * l];
            A[2 * i + 1] = p[2 * l + 1];
        }
        __builtin_amdgcn_sched_barrier(0);           // loads stay ABOVE uses

        if (w < 2) {   // keys: exp + Z + bf16
            #pragma unroll
            for (int i = 0; i < 8; ++i) {
                float4 a = A[2 * i], b = A[2 * i + 1];
                float e0 = __expf(a.x), e1 = __expf(a.y), e2 = __expf(a.z), e3 = __expf(a.w);
                float e4 = __expf(b.x), e5 = __expf(b.y), e6 = __expf(b.z), e7 = __expf(b.w);
                float z = ((e0 + e1) + (e2 + e3)) + ((e4 + e5) + (e6 + e7));
                #pragma unroll
                for (int off = 1; off < 64; off <<= 1) z += __shfl_xor(z, off);
                if (l == 0) zs[r0 + i] = z;          // fp32 Z BEFORE bf16 rounding
                short8 pk = {f2bf(e0), f2bf(e1), f2bf(e2), f2bf(e3),
                             f2bf(e4), f2bf(e5), f2bf(e6), f2bf(e7)};
                *(short8*)&e_s[r0 + i][l * 8] = pk;
            }
        } else {       // values: bf16 only
            #pragma unroll
            for (int i = 0; i < 8; ++i) {
                float4 a = A[2 * i], b = A[2 * i + 1];
                short8 pv = {f2bf(a.x), f2bf(a.y), f2bf(a.z), f2bf(a.w),
                             f2bf(b.x), f2bf(b.y), f2bf(b.z), f2bf(b.w)};
                *(short8*)&v_s[r0 + i][l * 8] = pv;
            }
        }
    }
    __syncthreads();

    // ---- compute: wave w -> cols [128w, 128w+128) = 4 K=32 MFMA steps
    int row16 = l & 15;               // kk for A, vv for B
    int q     = l >> 4;               // k-octet within K=32
    f32x4 acc = {0.f, 0.f, 0.f, 0.f};
    #pragma unroll
    for (int s = 0; s < 4; ++s) {
        int col = w * 128 + s * 32 + q * 8;
        short8 af = *(const short8*)&e_s[row16][col];
        short8 bv = *(const short8*)&v_s[row16][col];
        acc = __builtin_amdgcn_mfma_f32_16x16x32_bf16(af, bv, acc, 0, 0, 0);
    }

    // ---- ctx reduce: 4 wave partials over disjoint col-slices
    // D layout (m89-verified): lane l, reg r -> ctx[(l>>4)*4 + r][l&15]
    #pragma unroll
    for (int r = 0; r < 4; ++r)
        cred[w][(q * 4 + r) * 16 + row16] = acc[r];
    __syncthreads();

    if (tid < 16)
        ws[WS_ZP + (bh * CHUNKS + chunk) * 16 + tid] = zs[tid];
    float c = (cred[0][tid] + cred[1][tid]) + (cred[2][tid] + cred[3][tid]);
    ws[WS_PART + (size_t)(bh * CHUNKS + chunk) * 256 + tid] = c;   // [kk*16+vv]
}

// ---------------------------------------------------------------- kernel C
// Per (bh, 256-col block):
//   prologue: reduce 32 chunk-partials -> ctx[kk][vv] (normalized by Z[kk])
//   phase A : channel softmax of x2 columns (16 channels)
//   phase B : out[vv][n] = sum_kk ctx[kk][vv] * qsm[kk][n]
__global__ __launch_bounds__(256) void k_attend(const float* __restrict__ x2,
                                                const float* __restrict__ ws,
                                                float* __restrict__ out) {
    int cb  = blockIdx.x;   // 0..63 column block (256 cols)
    int bh  = blockIdx.y;   // 0..63
    int tid = threadIdx.x;

    __shared__ float q_s[16][256];   // k tile, then (in-place) qsm tile
    __shared__ float ctxs[256];
    __shared__ float rzs[16];

    // reduce partial context (L2/L3 hits; overlaps with tile load)
    float csum = 0.f;
    #pragma unroll
    for (int c = 0; c < CHUNKS; ++c)
        csum += ws[WS_PART + (size_t)(bh * CHUNKS + c) * 256 + tid];
    if (tid < 16) {
        float z = 0.f;
        #pragma unroll
        for (int c = 0; c < CHUNKS; ++c)
            z += ws[WS_ZP + (bh * CHUNKS + c) * 16 + tid];
        rzs[tid] = 1.0f / z;
    }

    const float4* px = (const float4*)(x2 + (size_t)bh * CH * N_);
    int base4 = cb * 64;             // 256 cols = 64 float4 per row
    #pragma unroll
    for (int r = 0; r < 4; ++r) {
        int idx = r * 256 + tid;
        int ch = idx >> 6, j = idx & 63;
        float4 v = px[(size_t)ch * N4 + base4 + j];
        *(float4*)&q_s[ch][j * 4] = v;
    }
    __syncthreads();

    ctxs[tid] = csum * rzs[tid >> 4];   // ctx[kk][vv], kk = tid>>4

    // phase A: thread = column; softmax over 16 channels, in place
    {
        int col = tid;
        float kv[16];
        #pragma unroll
        for (int c = 0; c < 16; ++c) kv[c] = q_s[c][col];
        float mx = kv[0];
        #pragma unroll
        for (int c = 1; c < 16; ++c) mx = fmaxf(mx, kv[c]);
        float s = 0.f;
        #pragma unroll
        for (int c = 0; c < 16; ++c) { kv[c] = __expf(kv[c] - mx); s += kv[c]; }
        float rs = 1.0f / s;
        #pragma unroll
        for (int c = 0; c < 16; ++c) q_s[c][col] = kv[c] * rs;
    }
    __syncthreads();

    // phase B: thread = (vg, cq); 4 vv x 4 cols register block
    int vg = tid >> 6, cq = tid & 63;
    int vv0 = vg * 4, c0 = cq * 4;
    float4 a0 = make_float4(0.f,0.f,0.f,0.f);
    float4 a1 = a0, a2 = a0, a3 = a0;   // a{c}[v]: col c, 4 vv's
    #pragma unroll
    for (int kk = 0; kk < 16; ++kk) {
        float4 cx = *(const float4*)&ctxs[kk * 16 + vv0];   // wave-uniform -> broadcast
        float4 q4 = *(const float4*)&q_s[kk][c0];
        a0.x = fmaf(q4.x, cx.x, a0.x); a0.y = fmaf(q4.x, cx.y, a0.y);
        a0.z = fmaf(q4.x, cx.z, a0.z); a0.w = fmaf(q4.x, cx.w, a0.w);
        a1.x = fmaf(q4.y, cx.x, a1.x); a1.y = fmaf(q4.y, cx.y, a1.y);
        a1.z = fmaf(q4.y, cx.z, a1.z); a1.w = fmaf(q4.y, cx.w, a1.w);
        a2.x = fmaf(q4.z, cx.x, a2.x); a2.y = fmaf(q4.z, cx.y, a2.y);
        a2.z = fmaf(q4.z, cx.z, a2.z); a2.w = fmaf(q4.z, cx.w, a2.w);
        a3.x = fmaf(q4.w, cx.x, a3.x); a3.y = fmaf(q4.w, cx.y, a3.y);
        a3.z = fmaf(q4.w, cx.z, a3.z); a3.w = fmaf(q4.w, cx.w, a3.w);
    }
    size_t outbase = (size_t)bh * CH * N_ + (size_t)cb * 256 + c0;
    float4 o;
    o = make_float4(a0.x, a1.x, a2.x, a3.x);
    *(float4*)&out[outbase + (size_t)(vv0 + 0) * N_] = o;
    o = make_float4(a0.y, a1.y, a2.y, a3.y);
    *(float4*)&out[outbase + (size_t)(vv0 + 1) * N_] = o;
    o = make_float4(a0.z, a1.z, a2.z, a3.z);
    *(float4*)&out[outbase + (size_t)(vv0 + 2) * N_] = o;
    o = make_float4(a0.w, a1.w, a2.w, a3.w);
    *(float4*)&out[outbase + (size_t)(vv0 + 3) * N_] = o;
}

// ---------------------------------------------------------------- launch
extern "C" void kernel_launch(void* const* d_in, const int* in_sizes, int n_in,
                              void* d_out, int out_size, void* d_ws, size_t ws_size,
                              hipStream_t stream) {
    const float* x1 = (const float*)d_in[0];   // values
    const float* x2 = (const float*)d_in[1];   // keys / queries
    float* out = (float*)d_out;
    float* ws  = (float*)d_ws;

    k_ctx_mfma <<<dim3(CHUNKS, BHN), 256, 0, stream>>>(x1, x2, ws);
    k_attend   <<<dim3(64, BHN),     256, 0, stream>>>(x2, ws, out);
}

// Round 15
// 53.845 us; speedup vs baseline: 1.4140x; 1.0679x over previous
//
#include <hip/hip_runtime.h>
#include <math.h>

// Problem constants: B=8, C=128, H=W=128, HEADS=8
#define N_     16384          // H*W
#define N4     4096           // N_/4 (float4 units per row)
#define BHN    64             // B*HEADS
#define CH     16             // channels per head (hk == hv)
#define CHUNKS 32             // col chunks for k_ctx (512 cols each)

// ws layout (in floats):
//   part[64*32*256] : unnormalized partial context per (bh, chunk)   2 MB
//   zp  [64*32*16]  : unnormalized partial row-sums               128 KB
#define WS_PART 0
#define WS_ZP   (BHN * CHUNKS * 256)

typedef __attribute__((ext_vector_type(8))) short short8;   // 8 x bf16
typedef __attribute__((ext_vector_type(4))) float f32x4;

static __device__ __forceinline__ short f2bf(float f) {
    __bf16 b = (__bf16)f;                      // v_cvt f32->bf16 (RNE)
    return __builtin_bit_cast(short, b);
}

// ---------------------------------------------------------------- kernel B
// ctx_part[kk][vv] = sum_{n in strip} exp(k[kk,n]) * v[vv,n]  via bf16 MFMA.
// UNCHANGED from r14 except comments. The r15 experiment lives in k_attend:
// nontemporal out-stores. Diagnosis r1-r14: k_ctx time == x1's 64MB HBM
// refetch at the structure-independent ~1.5 TB/s HBM-read rate (r13 pure-
// stream ablation); x2 is always L3-hot (FETCH == one array, never two).
// x1 is evicted each iteration by our own 64MB cache-allocating out-writes.
// Working set x1+x2+out+ws ~= 134MB < 256MB L3 -- if out stops allocating,
// x1 stays resident and the HBM refetch disappears in steady state.
__global__ __launch_bounds__(256, 2) void k_ctx_mfma(const float* __restrict__ x1,
                                                     const float* __restrict__ x2,
                                                     float* __restrict__ ws) {
    int chunk = blockIdx.x;   // 0..31 (512-col strip)
    int bh    = blockIdx.y;   // 0..63
    int tid   = threadIdx.x;
    int w = tid >> 6, l = tid & 63;

    __shared__ __align__(16) short e_s[16][520];   // exp'd keys, bf16
    __shared__ __align__(16) short v_s[16][520];   // values, bf16
    __shared__ float cred[4][256];
    __shared__ float zs[16];

    // ---- wave-specialized staging: ONE array per wave
    {
        const float* src = (w < 2) ? x2 : x1;
        int r0 = (w & 1) * 8;                       // rows r0..r0+7
        const float* base = src + (size_t)(bh * CH + r0) * N_ + chunk * 512;

        float4 A[16];                                // 16 independent loads
        #pragma unroll
        for (int i = 0; i < 8; ++i) {
            const float4* p = (const float4*)(base + (size_t)i * N_);
            A[2 * i]     = p[2 * l];
            A[2 * i + 1] = p[2 * l + 1];
        }
        __builtin_amdgcn_sched_barrier(0);           // loads stay ABOVE uses

        if (w < 2) {   // keys: exp + Z + bf16
            #pragma unroll
            for (int i = 0; i < 8; ++i) {
                float4 a = A[2 * i], b = A[2 * i + 1];
                float e0 = __expf(a.x), e1 = __expf(a.y), e2 = __expf(a.z), e3 = __expf(a.w);
                float e4 = __expf(b.x), e5 = __expf(b.y), e6 = __expf(b.z), e7 = __expf(b.w);
                float z = ((e0 + e1) + (e2 + e3)) + ((e4 + e5) + (e6 + e7));
                #pragma unroll
                for (int off = 1; off < 64; off <<= 1) z += __shfl_xor(z, off);
                if (l == 0) zs[r0 + i] = z;          // fp32 Z BEFORE bf16 rounding
                short8 pk = {f2bf(e0), f2bf(e1), f2bf(e2), f2bf(e3),
                             f2bf(e4), f2bf(e5), f2bf(e6), f2bf(e7)};
                *(short8*)&e_s[r0 + i][l * 8] = pk;
            }
        } else {       // values: bf16 only
            #pragma unroll
            for (int i = 0; i < 8; ++i) {
                float4 a = A[2 * i], b = A[2 * i + 1];
                short8 pv = {f2bf(a.x), f2bf(a.y), f2bf(a.z), f2bf(a.w),
                             f2bf(b.x), f2bf(b.y), f2bf(b.z), f2bf(b.w)};
                *(short8*)&v_s[r0 + i][l * 8] = pv;
            }
        }
    }
    __syncthreads();

    // ---- compute: wave w -> cols [128w, 128w+128) = 4 K=32 MFMA steps
    int row16 = l & 15;               // kk for A, vv for B
    int q     = l >> 4;               // k-octet within K=32
    f32x4 acc = {0.f, 0.f, 0.f, 0.f};
    #pragma unroll
    for (int s = 0; s < 4; ++s) {
        int col = w * 128 + s * 32 + q * 8;
        short8 af = *(const short8*)&e_s[row16][col];
        short8 bv = *(const short8*)&v_s[row16][col];
        acc = __builtin_amdgcn_mfma_f32_16x16x32_bf16(af, bv, acc, 0, 0, 0);
    }

    // ---- ctx reduce: 4 wave partials over disjoint col-slices
    // D layout (m89-verified): lane l, reg r -> ctx[(l>>4)*4 + r][l&15]
    #pragma unroll
    for (int r = 0; r < 4; ++r)
        cred[w][(q * 4 + r) * 16 + row16] = acc[r];
    __syncthreads();

    if (tid < 16)
        ws[WS_ZP + (bh * CHUNKS + chunk) * 16 + tid] = zs[tid];
    float c = (cred[0][tid] + cred[1][tid]) + (cred[2][tid] + cred[3][tid]);
    ws[WS_PART + (size_t)(bh * CHUNKS + chunk) * 256 + tid] = c;   // [kk*16+vv]
}

// ---------------------------------------------------------------- kernel C
// Per (bh, 256-col block): prologue reduce -> channel softmax -> ctx @ qsm.
// r15 CHANGE: out stores are NONTEMPORAL (gfx950 nt bit, no L3 allocation)
// -- out is never re-read, and its 64MB/iter of cache allocation is what
// evicts x1 (the diagnosed 45us HBM refetch in k_ctx).
__global__ __launch_bounds__(256) void k_attend(const float* __restrict__ x2,
                                                const float* __restrict__ ws,
                                                float* __restrict__ out) {
    int cb  = blockIdx.x;   // 0..63 column block (256 cols)
    int bh  = blockIdx.y;   // 0..63
    int tid = threadIdx.x;

    __shared__ float q_s[16][256];   // k tile, then (in-place) qsm tile
    __shared__ float ctxs[256];
    __shared__ float rzs[16];

    // reduce partial context (L2/L3 hits; overlaps with tile load)
    float csum = 0.f;
    #pragma unroll
    for (int c = 0; c < CHUNKS; ++c)
        csum += ws[WS_PART + (size_t)(bh * CHUNKS + c) * 256 + tid];
    if (tid < 16) {
        float z = 0.f;
        #pragma unroll
        for (int c = 0; c < CHUNKS; ++c)
            z += ws[WS_ZP + (bh * CHUNKS + c) * 16 + tid];
        rzs[tid] = 1.0f / z;
    }

    const float4* px = (const float4*)(x2 + (size_t)bh * CH * N_);
    int base4 = cb * 64;             // 256 cols = 64 float4 per row
    #pragma unroll
    for (int r = 0; r < 4; ++r) {
        int idx = r * 256 + tid;
        int ch = idx >> 6, j = idx & 63;
        float4 v = px[(size_t)ch * N4 + base4 + j];
        *(float4*)&q_s[ch][j * 4] = v;
    }
    __syncthreads();

    ctxs[tid] = csum * rzs[tid >> 4];   // ctx[kk][vv], kk = tid>>4

    // phase A: thread = column; softmax over 16 channels, in place
    {
        int col = tid;
        float kv[16];
        #pragma unroll
        for (int c = 0; c < 16; ++c) kv[c] = q_s[c][col];
        float mx = kv[0];
        #pragma unroll
        for (int c = 1; c < 16; ++c) mx = fmaxf(mx, kv[c]);
        float s = 0.f;
        #pragma unroll
        for (int c = 0; c < 16; ++c) { kv[c] = __expf(kv[c] - mx); s += kv[c]; }
        float rs = 1.0f / s;
        #pragma unroll
        for (int c = 0; c < 16; ++c) q_s[c][col] = kv[c] * rs;
    }
    __syncthreads();

    // phase B: thread = (vg, cq); 4 vv x 4 cols register block
    int vg = tid >> 6, cq = tid & 63;
    int vv0 = vg * 4, c0 = cq * 4;
    float4 a0 = make_float4(0.f,0.f,0.f,0.f);
    float4 a1 = a0, a2 = a0, a3 = a0;   // a{c}[v]: col c, 4 vv's
    #pragma unroll
    for (int kk = 0; kk < 16; ++kk) {
        float4 cx = *(const float4*)&ctxs[kk * 16 + vv0];   // wave-uniform -> broadcast
        float4 q4 = *(const float4*)&q_s[kk][c0];
        a0.x = fmaf(q4.x, cx.x, a0.x); a0.y = fmaf(q4.x, cx.y, a0.y);
        a0.z = fmaf(q4.x, cx.z, a0.z); a0.w = fmaf(q4.x, cx.w, a0.w);
        a1.x = fmaf(q4.y, cx.x, a1.x); a1.y = fmaf(q4.y, cx.y, a1.y);
        a1.z = fmaf(q4.y, cx.z, a1.z); a1.w = fmaf(q4.y, cx.w, a1.w);
        a2.x = fmaf(q4.z, cx.x, a2.x); a2.y = fmaf(q4.z, cx.y, a2.y);
        a2.z = fmaf(q4.z, cx.z, a2.z); a2.w = fmaf(q4.z, cx.w, a2.w);
        a3.x = fmaf(q4.w, cx.x, a3.x); a3.y = fmaf(q4.w, cx.y, a3.y);
        a3.z = fmaf(q4.w, cx.z, a3.z); a3.w = fmaf(q4.w, cx.w, a3.w);
    }
    size_t outbase = (size_t)bh * CH * N_ + (size_t)cb * 256 + c0;
    f32x4 o;
    o = (f32x4){a0.x, a1.x, a2.x, a3.x};
    __builtin_nontemporal_store(o, (f32x4*)(out + outbase + (size_t)(vv0 + 0) * N_));
    o = (f32x4){a0.y, a1.y, a2.y, a3.y};
    __builtin_nontemporal_store(o, (f32x4*)(out + outbase + (size_t)(vv0 + 1) * N_));
    o = (f32x4){a0.z, a1.z, a2.z, a3.z};
    __builtin_nontemporal_store(o, (f32x4*)(out + outbase + (size_t)(vv0 + 2) * N_));
    o = (f32x4){a0.w, a1.w, a2.w, a3.w};
    __builtin_nontemporal_store(o, (f32x4*)(out + outbase + (size_t)(vv0 + 3) * N_));
}

// ---------------------------------------------------------------- launch
extern "C" void kernel_launch(void* const* d_in, const int* in_sizes, int n_in,
                              void* d_out, int out_size, void* d_ws, size_t ws_size,
                              hipStream_t stream) {
    const float* x1 = (const float*)d_in[0];   // values
    const float* x2 = (const float*)d_in[1];   // keys / queries
    float* out = (float*)d_out;
    float* ws  = (float*)d_ws;

    k_ctx_mfma <<<dim3(CHUNKS, BHN), 256, 0, stream>>>(x1, x2, ws);
    k_attend   <<<dim3(64, BHN),     256, 0, stream>>>(x2, ws, out);
}